// Round 5
// baseline (14782.466 us; speedup 1.0000x reference)
//
#include <hip/hip_runtime.h>
#include <math.h>

// Problem constants
#define Gd   896
#define Bd   32
#define Td   1024
#define Cd   128
#define HDd  896
#define NWG  112
#define POISON 0xFFFFFFFFu
#define RETRY_MAX 16384

typedef short  short8 __attribute__((ext_vector_type(8)));
typedef float  f32x4  __attribute__((ext_vector_type(4)));
typedef unsigned int uint32;

__device__ __forceinline__ unsigned short f2bf(float f){
  unsigned u = __float_as_uint(f);
  u = u + 0x7FFFu + ((u >> 16) & 1u);      // RNE; never produces NaN from finite input
  return (unsigned short)(u >> 16);
}
__device__ __forceinline__ float bf2f(unsigned short h){
  return __uint_as_float(((unsigned)h) << 16);
}
__device__ __forceinline__ uint32 packbf(float v){
  unsigned short h = f2bf(v);
  unsigned short l = f2bf(v - bf2f(h));
  return ((uint32)h << 16) | (uint32)l;    // == POISON only if h=0xFFFF (NaN) -> impossible
}
__device__ __forceinline__ f32x4 mfma16(short8 a, short8 b, f32x4 c){
  return __builtin_amdgcn_mfma_f32_16x16x32_bf16(a, b, c, 0, 0, 0);
}
// LLC-coherent 4B accessors (agent scope, relaxed): pipeline like normal loads.
__device__ __forceinline__ uint32 aldw(const uint32* p){
  return __hip_atomic_load(p, __ATOMIC_RELAXED, __HIP_MEMORY_SCOPE_AGENT);
}
__device__ __forceinline__ void astw(uint32* p, uint32 v){
  __hip_atomic_store(p, v, __ATOMIC_RELAXED, __HIP_MEMORY_SCOPE_AGENT);
}

// ---------------------------------------------------------------------------
// Init: pack x -> (hi<<16|lo) dwords [b][t][c]; h0 -> [g][b] dwords in hb0;
// poison hb1..hb3.
// ---------------------------------------------------------------------------
__global__ void init_k(const float* __restrict__ x, const float* __restrict__ st,
                       uint32* __restrict__ x32, uint32* __restrict__ hb0,
                       uint32* __restrict__ hb1, uint32* __restrict__ hb2,
                       uint32* __restrict__ hb3)
{
  const long long tid  = (long long)blockIdx.x * blockDim.x + threadIdx.x;
  const long long nthr = (long long)gridDim.x * blockDim.x;
  const long long NX = (long long)Bd * Td * Cd;        // 4,194,304
  for (long long i = tid; i < NX; i += nthr) x32[i] = packbf(x[i]);
  const long long NH = (long long)Bd * Gd;             // 28,672
  for (long long i = tid; i < NH; i += nthr){
    int b = (int)(i / Gd), g = (int)(i % Gd);
    hb0[g * Bd + b] = packbf(st[i]);
    hb1[i] = POISON; hb2[i] = POISON; hb3[i] = POISON;
  }
}

// ---------------------------------------------------------------------------
// Persistent GRU. 112 WGs x 256 thr (1/CU, co-resident by construction).
// Waves: w0=(RZ,N0) w1=(RZ,N1) w2=(NP,N0) w3=(NP,N1).
//   RZ tile rows: [r 0..7 | z 0..7];  NP tile rows: [n 0..7 | post 0..7]
// Full-K per wave (28 h-kt + 4 x-kt), 3-chain compensated bf16 MFMA.
// Sync: NO flags, NO grid barrier. Consumers poll h data directly; producers
// poison next-next buffer at step start (4 rotating buffers; vmcnt FIFO
// retirement orders poison-ack before this step's data stores).
// ---------------------------------------------------------------------------
__global__ __launch_bounds__(256, 1)
void gru_persistent(const float* __restrict__ w_ih, const float* __restrict__ w_hh,
                    const float* __restrict__ b_ih, const float* __restrict__ b_hh,
                    const float* __restrict__ w_post, const float* __restrict__ b_post,
                    const uint32* __restrict__ x32,
                    uint32* __restrict__ hb0, uint32* __restrict__ hb1,
                    uint32* __restrict__ hb2, uint32* __restrict__ hb3,
                    float* __restrict__ out, float* __restrict__ hlast)
{
  const int wg   = blockIdx.x;
  const int tid  = threadIdx.x;
  const int w    = tid >> 6;
  const int lane = tid & 63;
  const int q    = lane >> 4;           // operand k-chunk / acc row-quad
  const int c    = lane & 15;           // A row m / B col n / acc col
  const int half = w & 1;               // batch half
  const bool T1  = (w & 2) != 0;        // false: RZ tile; true: N|POST tile
  const int b    = half * 16 + c;
  const int g0   = wg * 8;

  __shared__ float sR[2][2][8][17];     // [t&1][half][row][col] (+1 pad)
  __shared__ float sZ[2][2][8][17];

  // ---- Register-resident weights, hi/lo bf16 (kt 0..27 = w_hh/w_post cols,
  //      kt 28..31 = x region) ----
  short8 wfh[32], wfl[32];
  #pragma unroll
  for (int kt = 0; kt < 32; kt++){
    short8 sh, sl;
    #pragma unroll
    for (int j = 0; j < 8; j++){
      float v;
      if (kt < 28){
        int k = kt*32 + q*8 + j;
        if (!T1) v = w_hh[ (long long)((c < 8) ? (g0 + c) : (Gd + g0 + c - 8)) * Gd + k ];
        else     v = (c < 8) ? w_hh[ (long long)(2*Gd + g0 + c) * Gd + k ]
                             : w_post[ (long long)(g0 + c - 8) * Gd + k ];
      } else {
        int k = (kt - 28)*32 + q*8 + j;
        if (!T1) v = w_ih[ (long long)((c < 8) ? (g0 + c) : (Gd + g0 + c - 8)) * Cd + k ];
        else     v = (c < 8) ? w_ih[ (long long)(2*Gd + g0 + c) * Cd + k ] : 0.f;
      }
      unsigned short h = f2bf(v);
      sh[j] = (short)h; sl[j] = (short)f2bf(v - bf2f(h));
    }
    wfh[kt] = sh; wfl[kt] = sl;
  }

  // ---- Per-lane biases (acc rows 4q+i) ----
  float bA[4], bB[4];
  #pragma unroll
  for (int i = 0; i < 4; i++){
    if (!T1){
      if (q < 2){ int g = g0 + 4*q + i;       bA[i] = b_ih[g] + b_hh[g]; }
      else      { int g = g0 + 4*(q-2) + i;   bA[i] = b_ih[Gd+g] + b_hh[Gd+g]; }
      bB[i] = 0.f;
    } else {
      if (q < 2){ int nr = 2*Gd + g0 + 4*q + i; bA[i] = b_ih[nr]; bB[i] = b_hh[nr]; }
      else      { bA[i] = b_post[g0 + 4*(q-2) + i]; bB[i] = 0.f; }
    }
  }

  uint32* hbw[4] = { hb0, hb1, hb2, hb3 };
  const f32x4 zero4 = {0.f, 0.f, 0.f, 0.f};

  #pragma unroll 1
  for (int t = 0; t < Td; t++){
    const uint32* src = hbw[t & 3];          // h_t   (poll target)
    uint32*       dst = hbw[(t + 1) & 3];    // h_{t+1}
    uint32*       poi = hbw[(t + 2) & 3];    // poison ahead (safe: everyone past reading it)

    // poison own slice of the t+2 buffer FIRST (ordered before this step's
    // dst stores via in-order vmcnt retirement through the block-loop waits)
    if (T1 && q < 2){
      #pragma unroll
      for (int i = 0; i < 4; i++) astw(poi + (g0 + 4*q + i)*Bd + b, POISON);
    }

    f32x4 am = zero4, ac = zero4, ad = zero4;      // main tile accs
    f32x4 xm = zero4, xc = zero4, xdl = zero4;     // T1 x-part (n rows)

    // ---- x part (always ready; plain cached loads) ----
    {
      const uint32* xr = x32 + ((long long)b * Td + t) * Cd + q*8;
      #pragma unroll
      for (int kx = 0; kx < 4; kx++){
        short8 h8, l8;
        #pragma unroll
        for (int j = 0; j < 8; j++){
          uint32 d = xr[kx*32 + j];
          h8[j] = (short)(d >> 16); l8[j] = (short)(d & 0xFFFFu);
        }
        if (!T1){ am = mfma16(wfh[28+kx], h8, am); ac = mfma16(wfh[28+kx], l8, ac);
                  ad = mfma16(wfl[28+kx], h8, ad); }
        else    { xm = mfma16(wfh[28+kx], h8, xm); xc = mfma16(wfh[28+kx], l8, xc);
                  xdl = mfma16(wfl[28+kx], h8, xdl); }
      }
    }

    // ---- h part: 7 blocks x 4kt, poll-until-fresh, 2-slot pipeline ----
    uint32 bb_[2][32];
    #pragma unroll
    for (int s = 0; s < 2; s++)
      #pragma unroll
      for (int kk = 0; kk < 4; kk++)
        #pragma unroll
        for (int j = 0; j < 8; j++)
          bb_[s][kk*8+j] = aldw(src + (s*128 + kk*32 + q*8 + j)*Bd + b);

    #pragma unroll
    for (int blk = 0; blk < 7; blk++){
      uint32* cur = bb_[blk & 1];
      int tries = 0;
      for (;;){
        bool bad = false;
        #pragma unroll
        for (int j = 0; j < 32; j++) bad |= (cur[j] == POISON);
        if (!__any(bad)) break;
        if (++tries > RETRY_MAX) break;           // terminate (wrong) vs hang
        #pragma unroll
        for (int kk = 0; kk < 4; kk++)
          #pragma unroll
          for (int j = 0; j < 8; j++)
            cur[kk*8+j] = aldw(src + (blk*128 + kk*32 + q*8 + j)*Bd + b);
      }
      short8 h8[4], l8[4];
      #pragma unroll
      for (int kk = 0; kk < 4; kk++)
        #pragma unroll
        for (int j = 0; j < 8; j++){
          uint32 d = cur[kk*8+j];
          h8[kk][j] = (short)(d >> 16); l8[kk][j] = (short)(d & 0xFFFFu);
        }
      if (blk < 5){                               // prefetch blk+2 into freed slot
        #pragma unroll
        for (int kk = 0; kk < 4; kk++)
          #pragma unroll
          for (int j = 0; j < 8; j++)
            bb_[blk & 1][kk*8+j] = aldw(src + ((blk+2)*128 + kk*32 + q*8 + j)*Bd + b);
      }
      #pragma unroll
      for (int kk = 0; kk < 4; kk++){
        const int kt = blk*4 + kk;
        am = mfma16(wfh[kt], h8[kk], am);
        ac = mfma16(wfh[kt], l8[kk], ac);
        ad = mfma16(wfl[kt], h8[kk], ad);
      }
    }

    f32x4 s = (am + ac) + ad;

    // prefetch h_prev words for the update (off critical path, verified-fresh buffer)
    uint32 hpw[4];
    if (T1 && q < 2){
      #pragma unroll
      for (int i = 0; i < 4; i++) hpw[i] = aldw(src + (g0 + 4*q + i)*Bd + b);
    }

    if (!T1){
      #pragma unroll
      for (int i = 0; i < 4; i++){
        float v = s[i] + bA[i];
        float sg = 1.f / (1.f + __expf(-v));
        if (q < 2) sR[t & 1][half][4*q + i][c] = sg;
        else       sZ[t & 1][half][4*(q-2) + i][c] = sg;
      }
    }
    __syncthreads();

    if (T1){
      f32x4 sx = (xm + xc) + xdl;
      if (q < 2){
        uint32 dsto[4]; f32x4 hf;
        #pragma unroll
        for (int i = 0; i < 4; i++){
          float r  = sR[t & 1][half][4*q + i][c];
          float z  = sZ[t & 1][half][4*q + i][c];
          float hp = bf2f((unsigned short)(hpw[i] >> 16)) + bf2f((unsigned short)(hpw[i] & 0xFFFFu));
          float pre = (sx[i] + bA[i]) + r * (s[i] + bB[i]);
          float ax = fabsf(pre), e = __expf(-2.f * ax);
          float th = (1.f - e) / (1.f + e); th = (pre < 0.f) ? -th : th;
          float hv = (1.f - z) * th + z * hp;
          hf[i] = hv; dsto[i] = packbf(hv);
        }
        #pragma unroll
        for (int i = 0; i < 4; i++) astw(dst + (g0 + 4*q + i)*Bd + b, dsto[i]);
        if (t == Td - 1)
          *(f32x4*)(hlast + (long long)b * Gd + g0 + 4*q) = hf;
      } else if (t > 0){
        f32x4 o;
        #pragma unroll
        for (int i = 0; i < 4; i++){ float v = s[i] + bA[i]; o[i] = v > 0.f ? v : 0.f; }
        *(f32x4*)(out + ((long long)b * Td + (t - 1)) * HDd + g0 + 4*(q-2)) = o;
      }
    }
  }

  // ---- Epilogue: out[:,T-1,:] = relu(post . h_T + b); h_T is in hb[1024&3]=hb0 ----
  if (T1){
    const uint32* src = hbw[Td & 3];
    f32x4 am = zero4, ac = zero4, ad = zero4;
    uint32 bb_[2][32];
    #pragma unroll
    for (int sblk = 0; sblk < 2; sblk++)
      #pragma unroll
      for (int kk = 0; kk < 4; kk++)
        #pragma unroll
        for (int j = 0; j < 8; j++)
          bb_[sblk][kk*8+j] = aldw(src + (sblk*128 + kk*32 + q*8 + j)*Bd + b);
    #pragma unroll
    for (int blk = 0; blk < 7; blk++){
      uint32* cur = bb_[blk & 1];
      int tries = 0;
      for (;;){
        bool bad = false;
        #pragma unroll
        for (int j = 0; j < 32; j++) bad |= (cur[j] == POISON);
        if (!__any(bad)) break;
        if (++tries > RETRY_MAX) break;
        #pragma unroll
        for (int kk = 0; kk < 4; kk++)
          #pragma unroll
          for (int j = 0; j < 8; j++)
            cur[kk*8+j] = aldw(src + (blk*128 + kk*32 + q*8 + j)*Bd + b);
      }
      short8 h8[4], l8[4];
      #pragma unroll
      for (int kk = 0; kk < 4; kk++)
        #pragma unroll
        for (int j = 0; j < 8; j++){
          uint32 d = cur[kk*8+j];
          h8[kk][j] = (short)(d >> 16); l8[kk][j] = (short)(d & 0xFFFFu);
        }
      if (blk < 5){
        #pragma unroll
        for (int kk = 0; kk < 4; kk++)
          #pragma unroll
          for (int j = 0; j < 8; j++)
            bb_[blk & 1][kk*8+j] = aldw(src + ((blk+2)*128 + kk*32 + q*8 + j)*Bd + b);
      }
      #pragma unroll
      for (int kk = 0; kk < 4; kk++){
        const int kt = blk*4 + kk;
        am = mfma16(wfh[kt], h8[kk], am);
        ac = mfma16(wfh[kt], l8[kk], ac);
        ad = mfma16(wfl[kt], h8[kk], ad);
      }
    }
    f32x4 s = (am + ac) + ad;
    if (q >= 2){
      f32x4 o;
      #pragma unroll
      for (int i = 0; i < 4; i++){ float v = s[i] + bA[i]; o[i] = v > 0.f ? v : 0.f; }
      *(f32x4*)(out + ((long long)b * Td + (Td - 1)) * HDd + g0 + 4*(q-2)) = o;
    }
  }
}

// ---------------------------------------------------------------------------
extern "C" void kernel_launch(void* const* d_in, const int* in_sizes, int n_in,
                              void* d_out, int out_size, void* d_ws, size_t ws_size,
                              hipStream_t stream)
{
  const float* x      = (const float*)d_in[0];
  const float* state  = (const float*)d_in[1];
  const float* w_ih   = (const float*)d_in[2];
  const float* w_hh   = (const float*)d_in[3];
  const float* b_ih   = (const float*)d_in[4];
  const float* b_hh   = (const float*)d_in[5];
  const float* w_post = (const float*)d_in[6];
  const float* b_post = (const float*)d_in[7];

  float* out   = (float*)d_out;
  float* hlast = out + (long long)Bd * Td * HDd;

  // workspace: x32 16 MiB + 4 h buffers (112 KiB each) ~= 17.24 MB
  char* ws = (char*)d_ws;
  uint32* x32 = (uint32*)ws;                                   // 16,777,216 B
  uint32* hb0 = (uint32*)(ws + 16777216);                      //    114,688 B
  uint32* hb1 = (uint32*)(ws + 16891904);
  uint32* hb2 = (uint32*)(ws + 17006592);
  uint32* hb3 = (uint32*)(ws + 17121280);                      // end 17,235,968

  hipLaunchKernelGGL(init_k, dim3(2048), dim3(256), 0, stream,
                     x, state, x32, hb0, hb1, hb2, hb3);

  hipLaunchKernelGGL(gru_persistent, dim3(NWG), dim3(256), 0, stream,
                     w_ih, w_hh, b_ih, b_hh, w_post, b_post, x32,
                     hb0, hb1, hb2, hb3, out, hlast);
}